// Round 2
// baseline (170.484 us; speedup 1.0000x reference)
//
#include <hip/hip_runtime.h>
#include <hip/hip_bf16.h>

// Problem constants (fixed by reference setup: N=4096, D=512, C=100)
#define D_DIM 512
#define KSTEPS 16          // 512 / 32 (K per MFMA)
#define BM 128             // rows per block = 4 waves x 32 rows (2 slabs of 16)
#define BN 64              // columns per LDS tile
#define GRIDY 8            // column chunks across grid -> 64*8=512 blocks = 2/CU

typedef __bf16 bf16x8 __attribute__((ext_vector_type(8)));
typedef float  f32x4  __attribute__((ext_vector_type(4)));

__device__ __forceinline__ unsigned short f2bf_rne(float x) {
    unsigned int u = __float_as_uint(x);
    u += 0x7FFFu + ((u >> 16) & 1u);
    return (unsigned short)(u >> 16);
}

// rows [0,N): inst_embed -> instb ; rows [N,2N): proxy -> proxyb
__global__ __launch_bounds__(128) void normalize_rows(
    const float* __restrict__ inst, const float* __restrict__ proxy,
    unsigned short* __restrict__ instb, unsigned short* __restrict__ proxyb, int N)
{
    int row = blockIdx.x;
    const float* src;
    unsigned short* dst;
    if (row < N) { src = inst  + (size_t)row * D_DIM;        dst = instb  + (size_t)row * D_DIM; }
    else         { src = proxy + (size_t)(row - N) * D_DIM;  dst = proxyb + (size_t)(row - N) * D_DIM; }
    int t = threadIdx.x;                       // 128 threads x float4 = 512 elems
    float4 v = ((const float4*)src)[t];
    float ss = v.x*v.x + v.y*v.y + v.z*v.z + v.w*v.w;
    #pragma unroll
    for (int off = 32; off > 0; off >>= 1) ss += __shfl_down(ss, off, 64);
    __shared__ float wss[2];
    if ((t & 63) == 0) wss[t >> 6] = ss;
    __syncthreads();
    float inv = 1.0f / fmaxf(sqrtf(wss[0] + wss[1]), 1e-8f);
    ushort4 o;
    o.x = f2bf_rne(v.x * inv); o.y = f2bf_rne(v.y * inv);
    o.z = f2bf_rne(v.z * inv); o.w = f2bf_rne(v.w * inv);
    ((ushort4*)dst)[t] = o;
}

// Fused: sim tile via MFMA -> exp -> mask gather -> row-sum accumulate.
// Logical rows [0,N) = proxy rows (p2i), [N,2N) = inst rows (i2i). B is always inst.
// nd layout: [p2i_num | p2i_den | i2i_num | i2i_den], each N floats, pre-zeroed.
// LDS is FRAGMENT-MAJOR: chunk index (ks*4+cg)*64 + lane, 16B per chunk.
// Both staging writes and MFMA reads are base + lane*16B -> conflict-free.
__global__ __launch_bounds__(256, 2) void fused_scores(
    const unsigned short* __restrict__ instb,
    const unsigned short* __restrict__ proxyb,
    const float* __restrict__ negmask,   // [C, N]
    const int*  __restrict__ labels,     // [N]
    const float* __restrict__ temp_p,
    const float* __restrict__ margin_p,
    float* __restrict__ nd,
    int N, int colsPerBlock)
{
    __shared__ unsigned short Bt[BN * D_DIM];   // 64 KB fragment-major

    const int tid  = threadIdx.x;
    const int lane = tid & 63;
    const int wave = tid >> 6;      // 0..3
    const int quad = lane >> 4;     // 0..3
    const int l16  = lane & 15;

    const int Rbase  = blockIdx.x * BM + wave * 32;   // wave's 32 logical rows
    const bool isP2I = (Rbase < N);
    const unsigned short* Aptr = isP2I ? (proxyb + (size_t)Rbase * D_DIM)
                                       : (instb  + (size_t)(Rbase - N) * D_DIM);
    const int rowLocal = isP2I ? Rbase : (Rbase - N);

    const float temp  = *temp_p;
    const float scale = 1.44269504088896340736f / temp;   // log2(e)/t
    const float bias  = -(*margin_p) * scale;

    // Two A slabs resident in registers: A-layout A[m=l16][k=quad*8+j]
    bf16x8 Afrag[2][KSTEPS];
    #pragma unroll
    for (int s = 0; s < 2; s++) {
        const unsigned short* arow = Aptr + (size_t)(s * 16 + l16) * D_DIM + quad * 8;
        #pragma unroll
        for (int ks = 0; ks < KSTEPS; ks++)
            Afrag[s][ks] = *(const bf16x8*)(arow + ks * 32);
    }

    // labels for this lane's 8 output rows (C/D layout: row = quad*4 + reg)
    int lab[2][4];
    #pragma unroll
    for (int s = 0; s < 2; s++)
        #pragma unroll
        for (int r = 0; r < 4; r++)
            lab[s][r] = labels[rowLocal + s * 16 + quad * 4 + r];

    float numAcc[2][4] = {};
    float denAcc[2][4] = {};

    const int j0base = blockIdx.y * colsPerBlock;
    for (int jt = 0; jt < colsPerBlock; jt += BN) {
        const int j0 = j0base + jt;
        __syncthreads();   // protect previous tile's reads
        // Stage B tile fragment-major. Per wave-iter: one dc_hi = (ks*4+cg);
        // lane provides row = cg*16 + l16, k-chunk = ks*4 + (lane>>4).
        #pragma unroll
        for (int it = 0; it < 16; it++) {
            int dc_hi = it * 4 + wave;        // 0..63
            int ks = dc_hi >> 2;
            int cg = dc_hi & 3;
            const unsigned short* src =
                instb + (size_t)(j0 + cg * 16 + l16) * D_DIM + ks * 32 + quad * 8;
            *(bf16x8*)&Bt[(size_t)(dc_hi * 64 + lane) * 8] = *(const bf16x8*)src;
        }
        __syncthreads();

        f32x4 acc[2][4] = {};   // [slab][column group of 16]
        #pragma unroll
        for (int ks = 0; ks < KSTEPS; ks++) {
            #pragma unroll
            for (int cg = 0; cg < 4; cg++) {
                bf16x8 b = *(const bf16x8*)&Bt[(size_t)(((ks * 4 + cg) * 64) + lane) * 8];
                acc[0][cg] = __builtin_amdgcn_mfma_f32_16x16x32_bf16(Afrag[0][ks], b, acc[0][cg], 0, 0, 0);
                acc[1][cg] = __builtin_amdgcn_mfma_f32_16x16x32_bf16(Afrag[1][ks], b, acc[1][cg], 0, 0, 0);
            }
        }

        // Epilogue: zone = exp2(sim*scale + bias); accumulate den and masked num
        #pragma unroll
        for (int cg = 0; cg < 4; cg++) {
            int j = j0 + cg * 16 + l16;
            #pragma unroll
            for (int s = 0; s < 2; s++) {
                #pragma unroll
                for (int r = 0; r < 4; r++) {
                    float zone = exp2f(acc[s][cg][r] * scale + bias);
                    denAcc[s][r] += zone;
                    float m = negmask[(size_t)lab[s][r] * N + j];
                    numAcc[s][r] += zone * m;
                }
            }
        }
    }

    // Reduce across the 16 lanes (l16) sharing each output row, then atomicAdd
    float* numArr = nd + (isP2I ? 0 : 2 * N);
    float* denArr = numArr + N;
    #pragma unroll
    for (int s = 0; s < 2; s++) {
        #pragma unroll
        for (int r = 0; r < 4; r++) {
            float n = numAcc[s][r], d = denAcc[s][r];
            #pragma unroll
            for (int off = 8; off > 0; off >>= 1) {
                n += __shfl_down(n, off, 16);
                d += __shfl_down(d, off, 16);
            }
            if (l16 == 0) {
                int row = rowLocal + s * 16 + quad * 4 + r;
                atomicAdd(&numArr[row], n);
                atomicAdd(&denArr[row], d);
            }
        }
    }
}

__global__ __launch_bounds__(256) void loss_reduce(
    const float* __restrict__ nd, const float* __restrict__ temp_p,
    float* __restrict__ out, int N)
{
    const float t = *temp_p;
    float s = 0.f;
    for (int i = threadIdx.x; i < N; i += 256) {
        s -= logf(t * nd[i]         / nd[N + i]);       // p2i
        s -= logf(t * nd[2 * N + i] / nd[3 * N + i]);   // i2i
    }
    #pragma unroll
    for (int off = 32; off > 0; off >>= 1) s += __shfl_down(s, off, 64);
    __shared__ float wss[4];
    if ((threadIdx.x & 63) == 0) wss[threadIdx.x >> 6] = s;
    __syncthreads();
    if (threadIdx.x == 0) out[0] = (wss[0] + wss[1] + wss[2] + wss[3]) / (float)N;
}

extern "C" void kernel_launch(void* const* d_in, const int* in_sizes, int n_in,
                              void* d_out, int out_size, void* d_ws, size_t ws_size,
                              hipStream_t stream)
{
    const float* inst     = (const float*)d_in[0];
    const float* proxy    = (const float*)d_in[1];
    const float* negmask  = (const float*)d_in[2];
    const int*   labels   = (const int*)d_in[3];
    const float* temp_p   = (const float*)d_in[4];
    const float* margin_p = (const float*)d_in[5];
    float* out = (float*)d_out;

    const int N = in_sizes[3];    // 4096 (D fixed at 512 per reference)

    unsigned short* instb  = (unsigned short*)d_ws;
    unsigned short* proxyb = instb + (size_t)N * D_DIM;
    float* nd = (float*)(proxyb + (size_t)N * D_DIM);

    hipMemsetAsync(nd, 0, sizeof(float) * 4 * N, stream);
    normalize_rows<<<2 * N, 128, 0, stream>>>(inst, proxy, instb, proxyb, N);
    dim3 grid(2 * N / BM, GRIDY);
    fused_scores<<<grid, 256, 0, stream>>>(instb, proxyb, negmask, labels,
                                           temp_p, margin_p, nd, N, N / GRIDY);
    loss_reduce<<<1, 256, 0, stream>>>(nd, temp_p, out, N);
}

// Round 3
// 151.155 us; speedup vs baseline: 1.1279x; 1.1279x over previous
//
#include <hip/hip_runtime.h>
#include <hip/hip_bf16.h>

// Fixed by reference setup: N=4096, D=512, C=100
#define D_DIM 512

typedef __bf16 bf16x8 __attribute__((ext_vector_type(8)));
typedef float  f32x4  __attribute__((ext_vector_type(4)));

typedef unsigned int u32;
typedef __attribute__((address_space(1))) const u32 gl_u32;
typedef __attribute__((address_space(3))) u32 lds_u32;

// async 16B/lane global->LDS DMA; LDS dest is wave-uniform base + lane*16 (HW)
__device__ __forceinline__ void async_copy16(const void* gsrc, void* ldst) {
    __builtin_amdgcn_global_load_lds((gl_u32*)gsrc, (lds_u32*)ldst, 16, 0, 0);
}

__device__ __forceinline__ unsigned short f2bf_rne(float x) {
    unsigned int u = __float_as_uint(x);
    u += 0x7FFFu + ((u >> 16) & 1u);
    return (unsigned short)(u >> 16);
}

// One wave per row. Rows [0,N): inst, [N,2N): proxy. Output contiguous at `out`.
__global__ __launch_bounds__(256) void normalize_rows(
    const float* __restrict__ inst, const float* __restrict__ proxy,
    unsigned short* __restrict__ out, int N)
{
    int row  = blockIdx.x * 4 + (threadIdx.x >> 6);
    int lane = threadIdx.x & 63;
    const float* src = (row < N) ? inst + (size_t)row * D_DIM
                                 : proxy + (size_t)(row - N) * D_DIM;
    float4 v0 = ((const float4*)src)[lane];
    float4 v1 = ((const float4*)src)[lane + 64];
    float ss = v0.x*v0.x + v0.y*v0.y + v0.z*v0.z + v0.w*v0.w
             + v1.x*v1.x + v1.y*v1.y + v1.z*v1.z + v1.w*v1.w;
    #pragma unroll
    for (int off = 1; off < 64; off <<= 1) ss += __shfl_xor(ss, off, 64);
    float inv = 1.0f / fmaxf(sqrtf(ss), 1e-8f);
    unsigned short* dst = out + (size_t)row * D_DIM;
    ushort4 o0, o1;
    o0.x = f2bf_rne(v0.x*inv); o0.y = f2bf_rne(v0.y*inv);
    o0.z = f2bf_rne(v0.z*inv); o0.w = f2bf_rne(v0.w*inv);
    o1.x = f2bf_rne(v1.x*inv); o1.y = f2bf_rne(v1.y*inv);
    o1.z = f2bf_rne(v1.z*inv); o1.w = f2bf_rne(v1.w*inv);
    ((ushort4*)dst)[lane]      = o0;
    ((ushort4*)dst)[lane + 64] = o1;
}

// Outer-product GEMM + fused epilogue.
// Logical rows [0,N) = proxy (p2i), [N,2N) = inst (i2i); B cols are always inst rows.
// Block: 256 rows x 128 cols. Wave: 64 rows x 128 cols = 4x8 grid of 16x16 MFMA tiles.
// K staged in BK=64 slices: LDS = 32 A-frags + 16 B-frags, 1KB each (48 KB),
// fragment-major so global_load_lds's uniform-base+lane*16 lands each lane's
// MFMA operand chunk exactly where ds_read_b128 (base+lane*16) wants it.
// nd layout: [p2i_num | p2i_den | i2i_num | i2i_den], each N floats, pre-zeroed.
__global__ __launch_bounds__(256, 2) void fused_scores(
    const unsigned short* __restrict__ emb,   // [2N,512] bf16: inst rows then proxy rows
    const float* __restrict__ negmask,        // [C, N]
    const int*  __restrict__ labels,          // [N]
    const float* __restrict__ temp_p,
    const float* __restrict__ margin_p,
    float* __restrict__ nd, int N)
{
    __shared__ unsigned short TILE[48 * D_DIM / 8 * 8];   // 48 frags x 512 ushorts = 48 KB

    const int tid  = threadIdx.x;
    const int lane = tid & 63;
    const int wave = tid >> 6;      // 0..3
    const int quad = lane >> 4;     // 0..3
    const int l16  = lane & 15;

    const int Cbase = blockIdx.x * 128;     // B columns (inst rows)
    const int Rbase = blockIdx.y * 256;     // logical A rows
    const bool isP2I = (Rbase < N);
    // A rows in emb coordinates: proxy rows live at +N
    const int AbaseEmb = isP2I ? (N + Rbase) : (Rbase - N);
    const int rowLoc0  = (isP2I ? Rbase : (Rbase - N)) + wave * 64;

    const float temp  = *temp_p;
    const float scale = 1.44269504088896340736f / temp;   // log2(e)/t
    const float bias  = -(*margin_p) * scale;

    // Precompute this wave's 12 staging fragments: per-lane 32-bit byte offsets
    // from emb. Frag f<32: A frag (mt=f>>1, ks=f&1); f>=32: B frag.
    // Lane mapping per frag: row += (lane&15), kchunk = (lane>>4)*8 elems.
    unsigned fragOff[12];
    #pragma unroll
    for (int i = 0; i < 12; i++) {
        int f = wave * 12 + i;
        int sub = (f < 32) ? (f >> 1) : ((f - 32) >> 1);
        int ks  = f & 1;
        int rowE = (f < 32) ? (AbaseEmb + sub * 16 + l16)
                            : (Cbase    + sub * 16 + l16);
        fragOff[i] = (unsigned)((rowE * D_DIM + ks * 32 + quad * 8) * 2);
    }

    f32x4 acc[4][8] = {};   // [mi][nt] — 64 rows x 128 cols per wave

    for (int kit = 0; kit < 8; kit++) {       // K = 8 x 64
        __syncthreads();                      // previous tile fully consumed
        #pragma unroll
        for (int i = 0; i < 12; i++)
            async_copy16((const char*)emb + fragOff[i] + kit * 128,
                         &TILE[(wave * 12 + i) * 512]);
        __syncthreads();                      // drains vmcnt, DMA complete
        #pragma unroll
        for (int ks = 0; ks < 2; ks++) {
            bf16x8 a[4], b[8];
            #pragma unroll
            for (int mi = 0; mi < 4; mi++)
                a[mi] = *(const bf16x8*)&TILE[((wave * 4 + mi) * 2 + ks) * 512 + lane * 8];
            #pragma unroll
            for (int nt = 0; nt < 8; nt++)
                b[nt] = *(const bf16x8*)&TILE[(32 + nt * 2 + ks) * 512 + lane * 8];
            #pragma unroll
            for (int mi = 0; mi < 4; mi++)
                #pragma unroll
                for (int nt = 0; nt < 8; nt++)
                    acc[mi][nt] = __builtin_amdgcn_mfma_f32_16x16x32_bf16(
                        a[mi], b[nt], acc[mi][nt], 0, 0, 0);
        }
    }

    // Epilogue: zone = exp2(sim*scale+bias); per-row sums of zone and zone*mask.
    // C/D layout: col = l16, row = quad*4 + reg.
    float* numArr = nd + (isP2I ? 0 : 2 * N);
    float* denArr = numArr + N;
    #pragma unroll
    for (int mi = 0; mi < 4; mi++) {
        #pragma unroll
        for (int r = 0; r < 4; r++) {
            int row = rowLoc0 + mi * 16 + quad * 4 + r;
            int lab = labels[row];
            const float* mrow = negmask + (size_t)lab * N + Cbase + l16;
            float den = 0.f, num = 0.f;
            #pragma unroll
            for (int nt = 0; nt < 8; nt++) {
                float zone = exp2f(acc[mi][nt][r] * scale + bias);
                den += zone;
                num += zone * mrow[nt * 16];
            }
            #pragma unroll
            for (int off = 8; off > 0; off >>= 1) {
                num += __shfl_down(num, off, 16);
                den += __shfl_down(den, off, 16);
            }
            if (l16 == 0) {
                atomicAdd(&numArr[row], num);
                atomicAdd(&denArr[row], den);
            }
        }
    }
}

__global__ __launch_bounds__(256) void loss_reduce(
    const float* __restrict__ nd, const float* __restrict__ temp_p,
    float* __restrict__ out, int N)
{
    const float t = *temp_p;
    float s = 0.f;
    for (int i = threadIdx.x; i < N; i += 256) {
        s -= logf(t * nd[i]         / nd[N + i]);       // p2i
        s -= logf(t * nd[2 * N + i] / nd[3 * N + i]);   // i2i
    }
    #pragma unroll
    for (int off = 32; off > 0; off >>= 1) s += __shfl_down(s, off, 64);
    __shared__ float wss[4];
    if ((threadIdx.x & 63) == 0) wss[threadIdx.x >> 6] = s;
    __syncthreads();
    if (threadIdx.x == 0) out[0] = (wss[0] + wss[1] + wss[2] + wss[3]) / (float)N;
}

extern "C" void kernel_launch(void* const* d_in, const int* in_sizes, int n_in,
                              void* d_out, int out_size, void* d_ws, size_t ws_size,
                              hipStream_t stream)
{
    const float* inst     = (const float*)d_in[0];
    const float* proxy    = (const float*)d_in[1];
    const float* negmask  = (const float*)d_in[2];
    const int*   labels   = (const int*)d_in[3];
    const float* temp_p   = (const float*)d_in[4];
    const float* margin_p = (const float*)d_in[5];
    float* out = (float*)d_out;

    const int N = in_sizes[3];    // 4096 (D fixed at 512 per reference)

    unsigned short* emb = (unsigned short*)d_ws;          // [2N, 512] bf16
    float* nd = (float*)(emb + (size_t)2 * N * D_DIM);    // 4N floats

    hipMemsetAsync(nd, 0, sizeof(float) * 4 * N, stream);
    normalize_rows<<<2 * N / 4, 256, 0, stream>>>(inst, proxy, emb, N);
    dim3 grid(N / 128, 2 * N / 256);   // (32, 32)
    fused_scores<<<grid, 256, 0, stream>>>(emb, negmask, labels,
                                           temp_p, margin_p, nd, N);
    loss_reduce<<<1, 256, 0, stream>>>(nd, temp_p, out, N);
}

// Round 4
// 150.517 us; speedup vs baseline: 1.1327x; 1.0042x over previous
//
#include <hip/hip_runtime.h>
#include <hip/hip_bf16.h>

// Fixed by reference setup: N=4096, D=512, C=100
#define D_DIM 512
#define BK 32            // K elems staged per kit; 16 kits over D=512

typedef __bf16 bf16x8 __attribute__((ext_vector_type(8)));
typedef float  f32x4  __attribute__((ext_vector_type(4)));

typedef unsigned int u32;
typedef __attribute__((address_space(1))) const u32 gl_u32;
typedef __attribute__((address_space(3))) u32 lds_u32;

// async 16B/lane global->LDS DMA; LDS dest is wave-uniform base + lane*16 (HW)
__device__ __forceinline__ void async_copy16(const void* gsrc, void* ldst) {
    __builtin_amdgcn_global_load_lds((gl_u32*)gsrc, (lds_u32*)ldst, 16, 0, 0);
}

__device__ __forceinline__ unsigned short f2bf_rne(float x) {
    unsigned int u = __float_as_uint(x);
    u += 0x7FFFu + ((u >> 16) & 1u);
    return (unsigned short)(u >> 16);
}

// One wave per row. Rows [0,N): inst, [N,2N): proxy. Output contiguous at `out`.
__global__ __launch_bounds__(256) void normalize_rows(
    const float* __restrict__ inst, const float* __restrict__ proxy,
    unsigned short* __restrict__ out, int N)
{
    int row  = blockIdx.x * 4 + (threadIdx.x >> 6);
    int lane = threadIdx.x & 63;
    const float* src = (row < N) ? inst + (size_t)row * D_DIM
                                 : proxy + (size_t)(row - N) * D_DIM;
    float4 v0 = ((const float4*)src)[lane];
    float4 v1 = ((const float4*)src)[lane + 64];
    float ss = v0.x*v0.x + v0.y*v0.y + v0.z*v0.z + v0.w*v0.w
             + v1.x*v1.x + v1.y*v1.y + v1.z*v1.z + v1.w*v1.w;
    #pragma unroll
    for (int off = 1; off < 64; off <<= 1) ss += __shfl_xor(ss, off, 64);
    float inv = 1.0f / fmaxf(sqrtf(ss), 1e-8f);
    unsigned short* dst = out + (size_t)row * D_DIM;
    ushort4 o0, o1;
    o0.x = f2bf_rne(v0.x*inv); o0.y = f2bf_rne(v0.y*inv);
    o0.z = f2bf_rne(v0.z*inv); o0.w = f2bf_rne(v0.w*inv);
    o1.x = f2bf_rne(v1.x*inv); o1.y = f2bf_rne(v1.y*inv);
    o1.z = f2bf_rne(v1.z*inv); o1.w = f2bf_rne(v1.w*inv);
    ((ushort4*)dst)[lane]      = o0;
    ((ushort4*)dst)[lane + 64] = o1;
}

// Outer-product GEMM + fused epilogue, double-buffered async staging.
// Logical rows [0,N) = proxy (p2i), [N,2N) = inst (i2i); B cols are always inst rows.
// Block: 256 rows x 128 cols; wave: 64 rows x 128 cols = 4x8 grid of 16x16 tiles.
// Per kit (K=32): stage 24 frags (16 A + 8 B, 1KB each) into one of TWO distinct
// __shared__ buffers (distinct objects -> provable no-alias, so the compiler can
// keep next-kit DMAs in flight across this kit's ds_reads). One barrier per kit;
// its vmcnt(0) drain hits DMAs aged by a full compute phase -> cheap.
// nd layout: [p2i_num | p2i_den | i2i_num | i2i_den], each N floats, pre-zeroed.
__global__ __launch_bounds__(256, 2) void fused_scores(
    const unsigned short* __restrict__ emb,   // [2N,512] bf16: inst rows then proxy rows
    const float* __restrict__ negmask,        // [C, N]
    const int*  __restrict__ labels,          // [N]
    const float* __restrict__ temp_p,
    const float* __restrict__ margin_p,
    float* __restrict__ nd, int N)
{
    __shared__ unsigned short BUF0[24 * 512];   // 24 KB
    __shared__ unsigned short BUF1[24 * 512];   // 24 KB

    const int tid  = threadIdx.x;
    const int lane = tid & 63;
    const int wave = tid >> 6;      // 0..3
    const int quad = lane >> 4;     // 0..3
    const int l16  = lane & 15;

    const int Cbase = blockIdx.x * 128;     // B columns (inst rows)
    const int Rbase = blockIdx.y * 256;     // logical A rows
    const bool isP2I = (Rbase < N);
    const int AbaseEmb = isP2I ? (N + Rbase) : (Rbase - N);   // proxy rows at +N in emb
    const int rowLoc0  = (isP2I ? Rbase : (Rbase - N)) + wave * 64;

    const float temp  = *temp_p;
    const float scale = 1.44269504088896340736f / temp;   // log2(e)/t
    const float bias  = -(*margin_p) * scale;

    // This wave's 6 staging frags (frag f = wave*6+i): f<16 -> A row-group f,
    // f>=16 -> B col-group f-16. Lane mapping: row += l16, k-chunk = quad*8.
    unsigned fragOff[6];
    #pragma unroll
    for (int i = 0; i < 6; i++) {
        int f = wave * 6 + i;
        int rowE = (f < 16) ? (AbaseEmb + f * 16 + l16)
                            : (Cbase + (f - 16) * 16 + l16);
        fragOff[i] = (unsigned)((rowE * D_DIM + quad * 8) * 2);
    }

    f32x4 acc[4][8] = {};   // [mi][nt] — 64 rows x 128 cols per wave

    #define PREFETCH(buf, kit)                                                  \
        { _Pragma("unroll")                                                     \
          for (int i = 0; i < 6; i++)                                           \
              async_copy16((const char*)emb + fragOff[i] + ((unsigned)(kit) << 6), \
                           (buf) + (wave * 6 + i) * 512); }

    #define COMPUTE(buf)                                                        \
        { bf16x8 a_[4], b_[8];                                                  \
          _Pragma("unroll")                                                     \
          for (int mi = 0; mi < 4; mi++)                                        \
              a_[mi] = *(const bf16x8*)((buf) + (wave * 4 + mi) * 512 + lane * 8); \
          _Pragma("unroll")                                                     \
          for (int nt = 0; nt < 8; nt++)                                        \
              b_[nt] = *(const bf16x8*)((buf) + (16 + nt) * 512 + lane * 8);    \
          _Pragma("unroll")                                                     \
          for (int mi = 0; mi < 4; mi++)                                        \
              _Pragma("unroll")                                                 \
              for (int nt = 0; nt < 8; nt++)                                    \
                  acc[mi][nt] = __builtin_amdgcn_mfma_f32_16x16x32_bf16(        \
                      a_[mi], b_[nt], acc[mi][nt], 0, 0, 0); }

    PREFETCH(BUF0, 0)
    __syncthreads();
    for (int kit2 = 0; kit2 < 8; kit2++) {
        PREFETCH(BUF1, 2 * kit2 + 1)       // in flight across BUF0 compute
        COMPUTE(BUF0)
        __syncthreads();                   // drains aged BUF1 DMAs + BUF0 reads
        if (kit2 < 7) PREFETCH(BUF0, 2 * kit2 + 2)
        COMPUTE(BUF1)
        __syncthreads();
    }

    // Epilogue: zone = exp2(sim*scale+bias); per-row sums of zone and zone*mask.
    // C/D layout: col = l16, row = quad*4 + reg.
    float* numArr = nd + (isP2I ? 0 : 2 * N);
    float* denArr = numArr + N;
    #pragma unroll
    for (int mi = 0; mi < 4; mi++) {
        #pragma unroll
        for (int r = 0; r < 4; r++) {
            int row = rowLoc0 + mi * 16 + quad * 4 + r;
            int lab = labels[row];
            const float* mrow = negmask + (size_t)lab * N + Cbase + l16;
            float den = 0.f, num = 0.f;
            #pragma unroll
            for (int nt = 0; nt < 8; nt++) {
                float zone = exp2f(acc[mi][nt][r] * scale + bias);
                den += zone;
                num += zone * mrow[nt * 16];
            }
            #pragma unroll
            for (int off = 8; off > 0; off >>= 1) {
                num += __shfl_down(num, off, 16);
                den += __shfl_down(den, off, 16);
            }
            if (l16 == 0) {
                atomicAdd(&numArr[row], num);
                atomicAdd(&denArr[row], den);
            }
        }
    }
}

__global__ __launch_bounds__(256) void loss_reduce(
    const float* __restrict__ nd, const float* __restrict__ temp_p,
    float* __restrict__ out, int N)
{
    const float t = *temp_p;
    float s = 0.f;
    for (int i = threadIdx.x; i < N; i += 256) {
        s -= logf(t * nd[i]         / nd[N + i]);       // p2i
        s -= logf(t * nd[2 * N + i] / nd[3 * N + i]);   // i2i
    }
    #pragma unroll
    for (int off = 32; off > 0; off >>= 1) s += __shfl_down(s, off, 64);
    __shared__ float wss[4];
    if ((threadIdx.x & 63) == 0) wss[threadIdx.x >> 6] = s;
    __syncthreads();
    if (threadIdx.x == 0) out[0] = (wss[0] + wss[1] + wss[2] + wss[3]) / (float)N;
}

extern "C" void kernel_launch(void* const* d_in, const int* in_sizes, int n_in,
                              void* d_out, int out_size, void* d_ws, size_t ws_size,
                              hipStream_t stream)
{
    const float* inst     = (const float*)d_in[0];
    const float* proxy    = (const float*)d_in[1];
    const float* negmask  = (const float*)d_in[2];
    const int*   labels   = (const int*)d_in[3];
    const float* temp_p   = (const float*)d_in[4];
    const float* margin_p = (const float*)d_in[5];
    float* out = (float*)d_out;

    const int N = in_sizes[3];    // 4096 (D fixed at 512 per reference)

    unsigned short* emb = (unsigned short*)d_ws;          // [2N, 512] bf16
    float* nd = (float*)(emb + (size_t)2 * N * D_DIM);    // 4N floats

    hipMemsetAsync(nd, 0, sizeof(float) * 4 * N, stream);
    normalize_rows<<<2 * N / 4, 256, 0, stream>>>(inst, proxy, emb, N);
    dim3 grid(N / 128, 2 * N / 256);   // (32, 32)
    fused_scores<<<grid, 256, 0, stream>>>(emb, negmask, labels,
                                           temp_p, margin_p, nd, N);
    loss_reduce<<<1, 256, 0, stream>>>(nd, temp_p, out, N);
}